// Round 12
// baseline (763.414 us; speedup 1.0000x reference)
//
#include <hip/hip_runtime.h>
#include <hip/hip_bf16.h>

typedef __attribute__((ext_vector_type(4))) float f32x4;
typedef __attribute__((ext_vector_type(8))) __bf16 bf16x8;

#define DIMC 2048
#define NSEQ 2048
#define BATCH 2
#define HEADSC 16
#define DHEAD 128
#define ATTN_IN 2048
#define FF_IN 8192
#define FUSED_COLS 18688
#define ROWS 4096      // B*N
#define KCAT 10240     // ATTN_IN + FF_IN

// ---------------- workspace layout (bytes) ----------------
constexpr size_t OFF_XN   = 0;
constexpr size_t OFF_Q    = 16777216;
constexpr size_t OFF_K    = 33554432;
constexpr size_t OFF_VT   = 34603008;
constexpr size_t OFF_ACAT = 35651584;
constexpr size_t OFF_GATE = 119537664;
constexpr size_t OFF_WFT  = 186646528;
constexpr size_t OFF_WCT  = 263192576;
// dead-region reuse:
//   attn partials: O_part bf16 (41.9MB = 32bh x 40chunks x 128rows x 128d) over WFT;
//                  m/l fp32 over XN (dead after gemm1)
//   gemm2 split-K partials (bf16): P0 over XN [0,16MB), P1 over GATE (dead after silu)

// ---------------- LayerNorm -> bf16 ----------------
__global__ __launch_bounds__(256) void ln_kernel(const float* __restrict__ x,
                                                 const float* __restrict__ gamma,
                                                 __hip_bfloat16* __restrict__ xn) {
  int row = blockIdx.x;
  int tid = threadIdx.x;
  int lane = tid & 63, wave = tid >> 6;
  const float4* xr = (const float4*)(x + (size_t)row * DIMC);
  float4 a = xr[tid], b = xr[tid + 256];
  float s  = a.x + a.y + a.z + a.w + b.x + b.y + b.z + b.w;
  float ss = a.x*a.x + a.y*a.y + a.z*a.z + a.w*a.w + b.x*b.x + b.y*b.y + b.z*b.z + b.w*b.w;
  #pragma unroll
  for (int o = 32; o; o >>= 1) { s += __shfl_down(s, o); ss += __shfl_down(ss, o); }
  __shared__ float red[8];
  if (lane == 0) { red[wave] = s; red[4 + wave] = ss; }
  __syncthreads();
  s  = red[0] + red[1] + red[2] + red[3];
  ss = red[4] + red[5] + red[6] + red[7];
  float mean = s * (1.f / DIMC);
  float var  = ss * (1.f / DIMC) - mean * mean;
  float rstd = rsqrtf(var + 1e-5f);
  const float4* gp = (const float4*)gamma;
  float4 g1 = gp[tid], g2 = gp[tid + 256];
  __hip_bfloat16* o = xn + (size_t)row * DIMC;
  o[tid*4+0]      = __float2bfloat16((a.x - mean) * rstd * g1.x);
  o[tid*4+1]      = __float2bfloat16((a.y - mean) * rstd * g1.y);
  o[tid*4+2]      = __float2bfloat16((a.z - mean) * rstd * g1.z);
  o[tid*4+3]      = __float2bfloat16((a.w - mean) * rstd * g1.w);
  o[1024+tid*4+0] = __float2bfloat16((b.x - mean) * rstd * g2.x);
  o[1024+tid*4+1] = __float2bfloat16((b.y - mean) * rstd * g2.y);
  o[1024+tid*4+2] = __float2bfloat16((b.z - mean) * rstd * g2.z);
  o[1024+tid*4+3] = __float2bfloat16((b.w - mean) * rstd * g2.w);
}

// ---- fp32 [R][C] -> bf16 transposed dst[c*stride + off + r], 64x64 tile, bf16x8 writes ----
__global__ __launch_bounds__(256) void transpose_bf16(const float* __restrict__ src,
                                                      __hip_bfloat16* __restrict__ dst,
                                                      int R, int C, int dstStride, int dstOff) {
  __shared__ __align__(16) __hip_bfloat16 tile[64][72];
  int c0 = blockIdx.x * 64, r0 = blockIdx.y * 64;
  int tx = threadIdx.x & 15;
  int ty = threadIdx.x >> 4;
  #pragma unroll
  for (int i = 0; i < 64; i += 16) {
    float4 v = *(const float4*)(src + (size_t)(r0 + ty + i) * C + c0 + tx * 4);
    tile[tx*4+0][ty+i] = __float2bfloat16(v.x);
    tile[tx*4+1][ty+i] = __float2bfloat16(v.y);
    tile[tx*4+2][ty+i] = __float2bfloat16(v.z);
    tile[tx*4+3][ty+i] = __float2bfloat16(v.w);
  }
  __syncthreads();
  int rx = (threadIdx.x & 7) * 8;
  #pragma unroll
  for (int i = 0; i < 64; i += 32) {
    int cc = (threadIdx.x >> 3) + i;
    *(bf16x8*)(dst + (size_t)(c0 + cc) * dstStride + dstOff + r0 + rx) = *(const bf16x8*)&tile[cc][rx];
  }
}

// =========== 256x256 8-phase GEMM, m201-style read/wait discipline (round-9 best) ===========
struct GemmP {
  const __hip_bfloat16* A;
  const __hip_bfloat16* B;
  int K;
  int kTilesPer;
  int nbx;
  int nmn;
  int cpx;
  __hip_bfloat16* outF0;
  __hip_bfloat16* outF1;
  int Nout;
  __hip_bfloat16 *q, *kk, *vT, *acat, *gate;
};

#define LDA_Q(BUFIDX, QM) { \
    const char* slot_ = lds + ((BUFIDX) << 16) + ((QM) << 14); \
    _Pragma("unroll") for (int mi = 0; mi < 4; ++mi) \
    _Pragma("unroll") for (int ks = 0; ks < 2; ++ks) { \
      int row_ = (mi << 5) + (wr << 4) + (lane & 15); \
      int ch_  = (ks << 2) + (lane >> 4); \
      af[mi][ks] = *(const bf16x8*)(slot_ + (row_ << 7) + ((ch_ ^ (row_ & 7)) << 4)); } }

#define LDB_Q(DST, BUFIDX, QN) { \
    const char* slot_ = lds + ((BUFIDX) << 16) + 32768 + ((QN) << 14); \
    _Pragma("unroll") for (int ni = 0; ni < 2; ++ni) \
    _Pragma("unroll") for (int ks = 0; ks < 2; ++ks) { \
      int row_ = (ni << 6) + (wn << 4) + (lane & 15); \
      int ch_  = (ks << 2) + (lane >> 4); \
      DST[ni][ks] = *(const bf16x8*)(slot_ + (row_ << 7) + ((ch_ ^ (row_ & 7)) << 4)); } }

#define DO_MFMA_Q(QM, BSET, QN) \
    __builtin_amdgcn_s_setprio(1); \
    _Pragma("unroll") for (int mi = 0; mi < 4; ++mi) \
    _Pragma("unroll") for (int ni = 0; ni < 2; ++ni) \
    _Pragma("unroll") for (int ks = 0; ks < 2; ++ks) \
      acc[(QM)*4+mi][(QN)*2+ni] = __builtin_amdgcn_mfma_f32_16x16x32_bf16( \
          af[mi][ks], BSET[ni][ks], acc[(QM)*4+mi][(QN)*2+ni], 0, 0, 0); \
    __builtin_amdgcn_s_setprio(0);

#define KTILE_BODY(KT, BUFC) \
    LDB_Q(b0r, BUFC, 0); \
    LDA_Q(BUFC, 0); \
    stage(Bb, (KT) + 1, 1, 0); \
    asm volatile("s_waitcnt lgkmcnt(8)"); \
    __builtin_amdgcn_s_barrier(); \
    asm volatile("s_waitcnt lgkmcnt(0)"); \
    __builtin_amdgcn_sched_barrier(0); \
    DO_MFMA_Q(0, b0r, 0); \
    __builtin_amdgcn_s_barrier(); \
    LDB_Q(b1r, BUFC, 1); \
    stage(Bb, (KT) + 1, 1, 1); \
    __builtin_amdgcn_s_barrier(); \
    asm volatile("s_waitcnt lgkmcnt(0)"); \
    __builtin_amdgcn_sched_barrier(0); \
    DO_MFMA_Q(0, b1r, 1); \
    __builtin_amdgcn_s_barrier(); \
    LDA_Q(BUFC, 1); \
    stage(Ab, (KT) + 2, 0, 0); \
    __builtin_amdgcn_s_barrier(); \
    asm volatile("s_waitcnt lgkmcnt(0)"); \
    __builtin_amdgcn_sched_barrier(0); \
    DO_MFMA_Q(1, b0r, 0); \
    __builtin_amdgcn_s_barrier(); \
    stage(Ab, (KT) + 2, 0, 1); \
    asm volatile("s_waitcnt vmcnt(4)" ::: "memory"); \
    __builtin_amdgcn_sched_barrier(0); \
    __builtin_amdgcn_s_barrier(); \
    DO_MFMA_Q(1, b1r, 1);

template<int EPI>
__global__ __launch_bounds__(512, 2) void gemm256(GemmP p) {
  __shared__ __align__(16) char lds[131072];
  const int tid = threadIdx.x;
  const int lane = tid & 63, wave = tid >> 6;
  const int wr = wave >> 2, wn = wave & 3;

  int l = ((int)blockIdx.x & 7) * p.cpx + ((int)blockIdx.x >> 3);
  int kp = l / p.nmn;
  int r = l - kp * p.nmn;
  int per = 8 * p.nbx;
  int g = r / per;
  int rg = r - g * per;
  int by = (g << 3) + (rg & 7);
  int bx = rg >> 3;
  int m0 = by << 8, n0 = bx << 8;

  const int NT = p.kTilesPer;
  const size_t Kb = (size_t)p.K * 2;
  const size_t koff = (size_t)kp * NT * 128;
  const char* Ab = (const char*)p.A + (size_t)m0 * Kb + koff;
  const char* Bb = (const char*)p.B + (size_t)n0 * Kb + koff;

  auto stage = [&](const char* mbase, int ktTgt, int isB, int h) {
    int ks = ktTgt < NT ? ktTgt : NT - 1;
    char* dst = lds + ((ktTgt & 1) << 16) + (isB << 15) + (h << 14);
    #pragma unroll
    for (int j = 0; j < 2; ++j) {
      int c = (j << 9) + tid;
      int row = c >> 3;
      int gl = ((c & 7) ^ (row & 7)) << 4;
      __builtin_amdgcn_global_load_lds(
        (const __attribute__((address_space(1))) void*)(mbase + (size_t)((h << 7) + row) * Kb + (size_t)ks * 128 + gl),
        (__attribute__((address_space(3))) void*)(dst + (c << 4)), 16, 0, 0);
    }
  };

  bf16x8 af[4][2], b0r[2][2], b1r[2][2];
  f32x4 acc[8][4] = {};

  stage(Ab, 0, 0, 0); stage(Ab, 0, 0, 1);
  stage(Bb, 0, 1, 0); stage(Bb, 0, 1, 1);
  stage(Ab, 1, 0, 0); stage(Ab, 1, 0, 1);
  asm volatile("s_waitcnt vmcnt(4)" ::: "memory");
  __builtin_amdgcn_sched_barrier(0);
  __builtin_amdgcn_s_barrier();

  for (int kt = 0; kt < NT; kt += 2) {
    KTILE_BODY(kt, 0);
    KTILE_BODY(kt + 1, 1);
  }

  asm volatile("s_waitcnt vmcnt(0) lgkmcnt(0)" ::: "memory");

  if constexpr (EPI == 1) {
    #pragma unroll
    for (int mig = 0; mig < 8; ++mig) {
      int rr0 = m0 + (mig << 5) + (wr << 4) + ((lane >> 4) << 2);
      #pragma unroll
      for (int nig = 0; nig < 4; ++nig) {
        int cc = n0 + (nig << 6) + (wn << 4) + (lane & 15);
        #pragma unroll
        for (int rr_ = 0; rr_ < 4; ++rr_) {
          int rr = rr0 + rr_;
          int b = rr >> 11, n = rr & 2047;
          __hip_bfloat16 hv = __float2bfloat16(acc[mig][nig][rr_]);
          if (cc < 2048) {
            int h = cc >> 7, d = cc & 127;
            p.q[((((size_t)b << 4) + h) * NSEQ + n) * DHEAD + d] = hv;
          } else if (cc < 2176) {
            p.kk[(size_t)rr * DHEAD + (cc - 2048)] = hv;
          } else if (cc < 2304) {
            p.vT[(((size_t)b << 7) + (cc - 2176)) * NSEQ + n] = hv;
          } else if (cc < 10496) {
            p.acat[(size_t)rr * KCAT + (cc - 256)] = hv;
          } else {
            p.gate[(size_t)rr * FF_IN + (cc - 10496)] = hv;
          }
        }
      }
    }
  } else {
    __hip_bfloat16* dst = kp ? p.outF1 : p.outF0;
    #pragma unroll
    for (int mig = 0; mig < 8; ++mig) {
      int rr0 = m0 + (mig << 5) + (wr << 4) + ((lane >> 4) << 2);
      #pragma unroll
      for (int nig = 0; nig < 4; ++nig) {
        int cc = n0 + (nig << 6) + (wn << 4) + (lane & 15);
        #pragma unroll
        for (int rr_ = 0; rr_ < 4; ++rr_)
          dst[(size_t)(rr0 + rr_) * p.Nout + cc] = __float2bfloat16(acc[mig][nig][rr_]);
      }
    }
  }
}

// ---------------- split-K combine: bf16+bf16 -> fp32 out, x8 vectorized ----------------
__global__ __launch_bounds__(256) void addout_kernel(const __hip_bfloat16* __restrict__ a,
                                                     const __hip_bfloat16* __restrict__ b,
                                                     float* __restrict__ o, int n8) {
  int i = blockIdx.x * 256 + threadIdx.x;
  if (i < n8) {
    bf16x8 x = ((const bf16x8*)a)[i], y = ((const bf16x8*)b)[i];
    float4 o1, o2;
    o1.x = (float)x[0] + (float)y[0]; o1.y = (float)x[1] + (float)y[1];
    o1.z = (float)x[2] + (float)y[2]; o1.w = (float)x[3] + (float)y[3];
    o2.x = (float)x[4] + (float)y[4]; o2.y = (float)x[5] + (float)y[5];
    o2.z = (float)x[6] + (float)y[6]; o2.w = (float)x[7] + (float)y[7];
    ((float4*)o)[i * 2]     = o1;
    ((float4*)o)[i * 2 + 1] = o2;
  }
}

// ---------------- RoPE in place (k only; q fused into attn) ----------------
__global__ __launch_bounds__(256) void rope_kernel(__hip_bfloat16* __restrict__ t,
                                                   int totalRows, float scale) {
  int idx = blockIdx.x * 256 + threadIdx.x;
  if (idx >= totalRows * 64) return;
  int i = idx & 63;
  int row = idx >> 6;
  int n = row & (NSEQ - 1);
  float f = __expf(-(float)i * 0.14391157f);
  float ang = (float)n * f;
  float sv, cv;
  sincosf(ang, &sv, &cv);
  __hip_bfloat16* pp = t + (size_t)row * DHEAD;
  float x1 = __bfloat162float(pp[i]);
  float x2 = __bfloat162float(pp[i + 64]);
  pp[i]      = __float2bfloat16((x1 * cv - x2 * sv) * scale);
  pp[i + 64] = __float2bfloat16((x2 * cv + x1 * sv) * scale);
}

// ======== causal flash attention, split-KV partials (MQA), 32 q-rows/wave ========
// Block = (chunk c in [0,40), bh): qt16 of 128 q-rows; qt 0-3:1 chunk, 4-7:2, 8-11:3, 12-15:4.
// Chunk = up to 4 tiles of KVBLK=128. 4 waves x 32 q-rows (2 frags) -> each kf/vf LDS
// fragment feeds 2 MFMAs. LDS 80KB (K32+V32+P16) -> 2 blocks/CU. Counted-vmcnt pipeline:
// QK | bar | stageK(j+1) | vmcnt(8)[V(j)] | bar | softmax+PV | bar | stageV(j+1) |
// vmcnt(8)[K(j+1)] | bar.  No vmcnt(0) in loop.
__global__ __launch_bounds__(256, 2) void attn_part_kernel(const __hip_bfloat16* __restrict__ q,
                                                           const __hip_bfloat16* __restrict__ k,
                                                           const __hip_bfloat16* __restrict__ vT,
                                                           __hip_bfloat16* __restrict__ opart,
                                                           float* __restrict__ mpart,
                                                           float* __restrict__ lpart) {
  __shared__ __align__(16) char alds[81920];
  char* Ktile = alds;                 // 32KB: (j,ch): j*256 + (ch^swz)*16
  char* Vtile = alds + 32768;         // 32KB: (d,ch): d*256 + (ch^swz)*16
  char* Pb    = alds + 65536;         // 16KB: per-wave 4KB = 2 frags x [16][64] swz (kv-half)
  const int tid = threadIdx.x;
  int c = 39 - (int)blockIdx.x;       // longest chunks first
  int bh = blockIdx.y;
  int qt, ch;
  if (c < 4)       { qt = c;                  ch = 0; }
  else if (c < 12) { qt = 4  + ((c - 4) >> 1);  ch = (c - 4) & 1; }
  else if (c < 24) { qt = 8  + (c - 12) / 3;    ch = (c - 12) % 3; }
  else             { qt = 12 + ((c - 24) >> 2); ch = (c - 24) & 3; }
  int slot = bh * 40 + c;
  int b = bh >> 4;
  int lane = tid & 63, wave = tid >> 6;
  int q0 = qt << 7;
  int qrow0 = q0 + (wave << 5);       // 32 rows per wave
  const __hip_bfloat16* qbase = q + (size_t)bh * NSEQ * DHEAD;
  const char* kbase = (const char*)(k + (size_t)b * NSEQ * DHEAD);
  const char* vbase = (const char*)(vT + (size_t)b * DHEAD * NSEQ);
  char* Pw = Pb + (wave << 12);

  int nT = qt + 1;
  int jBeg = ch << 2;
  int jEnd = jBeg + 4 < nT ? jBeg + 4 : nT;

  auto stageK = [&](int j2) {
    int jc = j2 < jEnd ? j2 : jEnd - 1;
    const char* kb = kbase + (size_t)(jc << 7) * 256;
    #pragma unroll
    for (int it = 0; it < 8; ++it) {
      int s = (it << 8) + tid;
      int row = s >> 4, cch = s & 15;
      int sch = (cch & 8) | ((cch & 7) ^ (row & 7));
      __builtin_amdgcn_global_load_lds(
        (const __attribute__((address_space(1))) void*)(kb + (size_t)row * 256 + (sch << 4)),
        (__attribute__((address_space(3))) void*)(Ktile + (s << 4)), 16, 0, 0);
    }
  };
  auto stageV = [&](int j2) {
    int jc = j2 < jEnd ? j2 : jEnd - 1;
    const char* vb = vbase + (size_t)(jc << 7) * 2;
    #pragma unroll
    for (int it = 0; it < 8; ++it) {
      int s = (it << 8) + tid;
      int row = s >> 4, cch = s & 15;
      int sch = (cch & 8) | ((cch & 7) ^ (row & 7));
      __builtin_amdgcn_global_load_lds(
        (const __attribute__((address_space(1))) void*)(vb + (size_t)row * (NSEQ * 2) + (sch << 4)),
        (__attribute__((address_space(3))) void*)(Vtile + (s << 4)), 16, 0, 0);
    }
  };

  // Q fragments (2 x 16 rows) + fused RoPE + scale
  bf16x8 qf0[4], qf1[4];
  #pragma unroll
  for (int ks = 0; ks < 4; ++ks) {
    qf0[ks] = *(const bf16x8*)(qbase + (size_t)(qrow0 + (lane & 15)) * DHEAD + (ks << 5) + ((lane >> 4) << 3));
    qf1[ks] = *(const bf16x8*)(qbase + (size_t)(qrow0 + 16 + (lane & 15)) * DHEAD + (ks << 5) + ((lane >> 4) << 3));
  }
  {
    const float SCALE = 0.08838834764831845f;
    float n0f = (float)(qrow0 + (lane & 15));
    float n1f = n0f + 16.f;
    #pragma unroll
    for (int ks = 0; ks < 2; ++ks) {
      #pragma unroll
      for (int j = 0; j < 8; ++j) {
        int d = (ks << 5) + ((lane >> 4) << 3) + j;
        float f = __expf(-(float)d * 0.14391157f);
        float sv, cv;
        sincosf(n0f * f, &sv, &cv);
        float x1 = (float)qf0[ks][j], x2 = (float)qf0[ks + 2][j];
        qf0[ks][j]     = (__bf16)((x1 * cv - x2 * sv) * SCALE);
        qf0[ks + 2][j] = (__bf16)((x2 * cv + x1 * sv) * SCALE);
        sincosf(n1f * f, &sv, &cv);
        float y1 = (float)qf1[ks][j], y2 = (float)qf1[ks + 2][j];
        qf1[ks][j]     = (__bf16)((y1 * cv - y2 * sv) * SCALE);
        qf1[ks + 2][j] = (__bf16)((y2 * cv + y1 * sv) * SCALE);
      }
    }
  }

  f32x4 o0[8] = {}, o1[8] = {};
  float m0r[4] = {-1e30f, -1e30f, -1e30f, -1e30f}, m1r[4] = {-1e30f, -1e30f, -1e30f, -1e30f};
  float l0r[4] = {0.f, 0.f, 0.f, 0.f}, l1r[4] = {0.f, 0.f, 0.f, 0.f};

  // prologue: K(jBeg), V(jBeg); vmcnt(8) proves K; V hides under first QK
  stageK(jBeg);
  stageV(jBeg);
  asm volatile("s_waitcnt vmcnt(8)" ::: "memory");
  __builtin_amdgcn_s_barrier();

  for (int j2 = jBeg; j2 < jEnd; ++j2) {
    int j0 = j2 << 7;
    f32x4 s0[8] = {}, s1[8] = {};
    // ---- QK (V(j) loads in flight underneath) ----
    #pragma unroll
    for (int ks = 0; ks < 4; ++ks) {
      bf16x8 kf2[8];
      #pragma unroll
      for (int nf = 0; nf < 8; ++nf) {
        int row_ = (nf << 4) + (lane & 15);
        int ch_  = (ks << 2) + (lane >> 4);
        int sch  = (ch_ & 8) | ((ch_ & 7) ^ (row_ & 7));
        kf2[nf] = *(const bf16x8*)(Ktile + (row_ << 8) + (sch << 4));
      }
      __builtin_amdgcn_s_setprio(1);
      #pragma unroll
      for (int nf = 0; nf < 8; ++nf)
        s0[nf] = __builtin_amdgcn_mfma_f32_16x16x32_bf16(qf0[ks], kf2[nf], s0[nf], 0, 0, 0);
      #pragma unroll
      for (int nf = 0; nf < 8; ++nf)
        s1[nf] = __builtin_amdgcn_mfma_f32_16x16x32_bf16(qf1[ks], kf2[nf], s1[nf], 0, 0, 0);
      __builtin_amdgcn_s_setprio(0);
    }
    __builtin_amdgcn_s_barrier();             // Ktile free
    stageK(j2 + 1);
    asm volatile("s_waitcnt vmcnt(8)" ::: "memory");   // V(j) landed
    __builtin_amdgcn_s_barrier();             // Vtile valid for all waves
    // ---- mask ----
    if (j0 + 127 > q0) {
      #pragma unroll
      for (int nf = 0; nf < 8; ++nf) {
        int cg = j0 + (nf << 4) + (lane & 15);
        #pragma unroll
        for (int r = 0; r < 4; ++r) {
          int rg0 = qrow0 + ((lane >> 4) << 2) + r;
          if (cg > rg0) s0[nf][r] = -1e30f;
          if (cg > rg0 + 16) s1[nf][r] = -1e30f;
        }
      }
    }
    // ---- online softmax (both frags) ----
    float tm0[4] = {-1e30f, -1e30f, -1e30f, -1e30f}, tm1[4] = {-1e30f, -1e30f, -1e30f, -1e30f};
    #pragma unroll
    for (int nf = 0; nf < 8; ++nf)
      #pragma unroll
      for (int r = 0; r < 4; ++r) { tm0[r] = fmaxf(tm0[r], s0[nf][r]); tm1[r] = fmaxf(tm1[r], s1[nf][r]); }
    #pragma unroll
    for (int r = 0; r < 4; ++r) {
      #pragma unroll
      for (int msk = 1; msk < 16; msk <<= 1) {
        tm0[r] = fmaxf(tm0[r], __shfl_xor(tm0[r], msk));
        tm1[r] = fmaxf(tm1[r], __shfl_xor(tm1[r], msk));
      }
    }
    float sc0[4], sc1[4], ps0[4] = {}, ps1[4] = {};
    #pragma unroll
    for (int r = 0; r < 4; ++r) {
      float mn0 = fmaxf(m0r[r], tm0[r]);
      sc0[r] = __expf(m0r[r] - mn0); m0r[r] = mn0;
      float mn1 = fmaxf(m1r[r], tm1[r]);
      sc1[r] = __expf(m1r[r] - mn1); m1r[r] = mn1;
    }
    #pragma unroll
    for (int nf = 0; nf < 8; ++nf) {
      #pragma unroll
      for (int r = 0; r < 4; ++r) {
        float p0 = __expf(s0[nf][r] - m0r[r]); ps0[r] += p0; s0[nf][r] = p0;
        float p1 = __expf(s1[nf][r] - m1r[r]); ps1[r] += p1; s1[nf][r] = p1;
      }
    }
    #pragma unroll
    for (int r = 0; r < 4; ++r) {
      #pragma unroll
      for (int msk = 1; msk < 16; msk <<= 1) { ps0[r] += __shfl_xor(ps0[r], msk); ps1[r] += __shfl_xor(ps1[r], msk); }
      l0r[r] = l0r[r] * sc0[r] + ps0[r];
      l1r[r] = l1r[r] * sc1[r] + ps1[r];
    }
    #pragma unroll
    for (int df = 0; df < 8; ++df)
      #pragma unroll
      for (int r = 0; r < 4; ++r) { o0[df][r] *= sc0[r]; o1[df][r] *= sc1[r]; }
    // ---- PV in two kv-halves; P per-wave (no barrier) ----
    #pragma unroll
    for (int half = 0; half < 2; ++half) {
      // write P half for both frags: [frag][16 rows][64 cols] chunk-swizzled
      #pragma unroll
      for (int nf4 = 0; nf4 < 4; ++nf4) {
        int nf = (half << 2) + nf4;
        int col = (nf4 << 4) + (lane & 15);
        int pch = col >> 3, inb = (col & 7) << 1;
        #pragma unroll
        for (int r = 0; r < 4; ++r) {
          int prow = ((lane >> 4) << 2) + r;
          int psch = pch ^ (prow & 7);
          *(__hip_bfloat16*)(Pw + (prow << 7) + (psch << 4) + inb) = __float2bfloat16(s0[nf][r]);
          *(__hip_bfloat16*)(Pw + 2048 + (prow << 7) + (psch << 4) + inb) = __float2bfloat16(s1[nf][r]);
        }
      }
      #pragma unroll
      for (int k2 = 0; k2 < 2; ++k2) {
        int ks2 = (half << 1) + k2;
        int prow = lane & 15;
        int pch = (k2 << 2) + (lane >> 4);
        int psch = pch ^ (prow & 7);
        bf16x8 pf0 = *(const bf16x8*)(Pw + (prow << 7) + (psch << 4));
        bf16x8 pf1 = *(const bf16x8*)(Pw + 2048 + (prow << 7) + (psch << 4));
        bf16x8 vf2[8];
        #pragma unroll
        for (int df = 0; df < 8; ++df) {
          int row_ = (df << 4) + (lane & 15);
          int ch_  = (ks2 << 2) + (lane >> 4);
          int sch  = (ch_ & 8) | ((ch_ & 7) ^ (row_ & 7));
          vf2[df] = *(const bf16x8*)(Vtile + (row_ << 8) + (sch << 4));
        }
        __builtin_amdgcn_s_setprio(1);
        #pragma unroll
        for (int df = 0; df < 8; ++df)
          o0[df] = __builtin_amdgcn_mfma_f32_16x16x32_bf16(pf0, vf2[df], o0[df], 0, 0, 0);
        #pragma unroll
        for (int df = 0; df < 8; ++df)
          o1[df] = __builtin_amdgcn_mfma_f32_16x16x32_bf16(pf1, vf2[df], o1[df], 0, 0, 0);
        __builtin_amdgcn_s_setprio(0);
      }
    }
    __builtin_amdgcn_s_barrier();             // Vtile free
    stageV(j2 + 1);
    asm volatile("s_waitcnt vmcnt(8)" ::: "memory");   // K(j+1) landed (hid under softmax+PV)
    __builtin_amdgcn_s_barrier();             // Ktile(j+1) valid
  }
  asm volatile("s_waitcnt vmcnt(0)" ::: "memory");     // drain tail V stage before exit

  size_t rb0 = ((size_t)slot << 7) + (wave << 5) + ((lane >> 4) << 2);
  #pragma unroll
  for (int df = 0; df < 8; ++df)
    #pragma unroll
    for (int r = 0; r < 4; ++r) {
      opart[(rb0 + r) * 128 + (df << 4) + (lane & 15)] = __float2bfloat16(o0[df][r]);
      opart[(rb0 + 16 + r) * 128 + (df << 4) + (lane & 15)] = __float2bfloat16(o1[df][r]);
    }
  if ((lane & 15) == 0) {
    #pragma unroll
    for (int r = 0; r < 4; ++r) {
      mpart[rb0 + r] = m0r[r];      lpart[rb0 + r] = l0r[r];
      mpart[rb0 + 16 + r] = m1r[r]; lpart[rb0 + 16 + r] = l1r[r];
    }
  }
}

// combine: per (bh,row,8d) merge <=4 chunks (40-chunk table); write acat attention cols
__global__ __launch_bounds__(256) void attn_comb_kernel(const __hip_bfloat16* __restrict__ opart,
                                                        const float* __restrict__ mpart,
                                                        const float* __restrict__ lpart,
                                                        __hip_bfloat16* __restrict__ acat) {
  int t = blockIdx.x * 256 + threadIdx.x;
  int dg = t & 15;
  int rg = (t >> 4) & 2047;
  int bh = t >> 15;
  int qt = rg >> 7;                 // 128-row tiles
  int nc = (qt >> 2) + 1;
  int S;
  if (qt < 4)       S = qt;
  else if (qt < 8)  S = 4 + 2 * (qt - 4);
  else if (qt < 12) S = 12 + 3 * (qt - 8);
  else              S = 24 + 4 * (qt - 12);
  size_t base = (((size_t)bh * 40 + S) << 7) + (rg & 127);
  float M = -1e30f;
  for (int cc = 0; cc < nc; ++cc) M = fmaxf(M, mpart[base + ((size_t)cc << 7)]);
  float O[8] = {};
  float L = 0.f;
  for (int cc = 0; cc < nc; ++cc) {
    size_t rb = base + ((size_t)cc << 7);
    float w = __expf(mpart[rb] - M);
    L += w * lpart[rb];
    bf16x8 ov = *(const bf16x8*)(opart + rb * 128 + (dg << 3));
    #pragma unroll
    for (int j = 0; j < 8; ++j) O[j] += w * (float)ov[j];
  }
  float invL = 1.f / L;
  int b = bh >> 4, h = bh & 15;
  bf16x8 res;
  #pragma unroll
  for (int j = 0; j < 8; ++j) res[j] = (__bf16)(O[j] * invL);
  *(bf16x8*)(acat + ((size_t)(b * 2048 + rg)) * KCAT + (h << 7) + (dg << 3)) = res;
}

// ---------------- silu(gate) * ff_x, in place on Acat (bf16x8) ----------------
__global__ __launch_bounds__(256) void silu_kernel(__hip_bfloat16* __restrict__ acat,
                                                   const __hip_bfloat16* __restrict__ gate) {
  size_t idx = ((size_t)blockIdx.x * 256 + threadIdx.x) << 3;
  int r = (int)(idx >> 13);
  int j = (int)(idx & 8191);
  bf16x8 g = *(const bf16x8*)(gate + idx);
  size_t ai = (size_t)r * KCAT + 2048 + j;
  bf16x8 fx = *(const bf16x8*)(acat + ai);
  bf16x8 res;
  #pragma unroll
  for (int t = 0; t < 8; ++t) {
    float gf = (float)g[t];
    res[t] = (__bf16)((float)fx[t] * gf / (1.f + __expf(-gf)));
  }
  *(bf16x8*)(acat + ai) = res;
}

extern "C" void kernel_launch(void* const* d_in, const int* in_sizes, int n_in,
                              void* d_out, int out_size, void* d_ws, size_t ws_size,
                              hipStream_t stream) {
  (void)in_sizes; (void)n_in; (void)out_size; (void)ws_size;
  const float* x          = (const float*)d_in[0];
  const float* gamma      = (const float*)d_in[1];
  const float* w_fused    = (const float*)d_in[2];
  const float* w_attn_out = (const float*)d_in[3];
  const float* w_ff_out   = (const float*)d_in[4];
  char* ws = (char*)d_ws;
  __hip_bfloat16* xn    = (__hip_bfloat16*)(ws + OFF_XN);
  __hip_bfloat16* qbuf  = (__hip_bfloat16*)(ws + OFF_Q);
  __hip_bfloat16* kbuf  = (__hip_bfloat16*)(ws + OFF_K);
  __hip_bfloat16* vTbuf = (__hip_bfloat16*)(ws + OFF_VT);
  __hip_bfloat16* acat  = (__hip_bfloat16*)(ws + OFF_ACAT);
  __hip_bfloat16* gateb = (__hip_bfloat16*)(ws + OFF_GATE);
  __hip_bfloat16* wfT   = (__hip_bfloat16*)(ws + OFF_WFT);
  __hip_bfloat16* wcT   = (__hip_bfloat16*)(ws + OFF_WCT);
  __hip_bfloat16* P0 = (__hip_bfloat16*)(ws + OFF_XN);
  __hip_bfloat16* P1 = (__hip_bfloat16*)(ws + OFF_GATE);
  __hip_bfloat16* oPart = (__hip_bfloat16*)(ws + OFF_WFT);
  float* mPart = (float*)(ws + OFF_XN);
  float* lPart = (float*)(ws + OFF_XN + 1048576);

  transpose_bf16<<<dim3(FUSED_COLS / 64, DIMC / 64), 256, 0, stream>>>(w_fused, wfT, DIMC, FUSED_COLS, DIMC, 0);
  transpose_bf16<<<dim3(DIMC / 64, DIMC / 64), 256, 0, stream>>>(w_attn_out, wcT, ATTN_IN, DIMC, KCAT, 0);
  transpose_bf16<<<dim3(DIMC / 64, FF_IN / 64), 256, 0, stream>>>(w_ff_out, wcT, FF_IN, DIMC, KCAT, ATTN_IN);

  ln_kernel<<<ROWS, 256, 0, stream>>>(x, gamma, xn);

  GemmP g1;
  g1.A = xn; g1.B = wfT; g1.K = DIMC; g1.kTilesPer = DIMC / 64;
  g1.nbx = FUSED_COLS / 256; g1.nmn = (FUSED_COLS / 256) * (ROWS / 256);
  g1.cpx = g1.nmn / 8;
  g1.outF0 = nullptr; g1.outF1 = nullptr; g1.Nout = 0;
  g1.q = qbuf; g1.kk = kbuf; g1.vT = vTbuf; g1.acat = acat; g1.gate = gateb;
  gemm256<1><<<g1.nmn, 512, 0, stream>>>(g1);

  rope_kernel<<<(BATCH * NSEQ * 64) / 256, 256, 0, stream>>>(kbuf, BATCH * NSEQ, 1.0f);

  attn_part_kernel<<<dim3(40, BATCH * HEADSC), 256, 0, stream>>>(qbuf, kbuf, vTbuf, oPart, mPart, lPart);
  attn_comb_kernel<<<(BATCH * HEADSC * NSEQ * DHEAD / 8) / 256, 256, 0, stream>>>(oPart, mPart, lPart, acat);

  silu_kernel<<<(int)(((size_t)ROWS * FF_IN / 8) / 256), 256, 0, stream>>>(acat, gateb);

  GemmP g2;
  g2.A = acat; g2.B = wcT; g2.K = KCAT; g2.kTilesPer = (KCAT / 64) / 2;
  g2.nbx = DIMC / 256; g2.nmn = (DIMC / 256) * (ROWS / 256);
  g2.cpx = (g2.nmn * 2) / 8;
  g2.outF0 = P0; g2.outF1 = P1; g2.Nout = DIMC;
  g2.q = nullptr; g2.kk = nullptr; g2.vT = nullptr; g2.acat = nullptr; g2.gate = nullptr;
  gemm256<3><<<g2.nmn * 2, 512, 0, stream>>>(g2);

  addout_kernel<<<(ROWS * DIMC / 8 + 255) / 256, 256, 0, stream>>>(P0, P1, (float*)d_out, ROWS * DIMC / 8);
}

// Round 13
// 695.461 us; speedup vs baseline: 1.0977x; 1.0977x over previous
//
#include <hip/hip_runtime.h>
#include <hip/hip_bf16.h>

typedef __attribute__((ext_vector_type(4))) float f32x4;
typedef __attribute__((ext_vector_type(8))) __bf16 bf16x8;

#define DIMC 2048
#define NSEQ 2048
#define BATCH 2
#define HEADSC 16
#define DHEAD 128
#define ATTN_IN 2048
#define FF_IN 8192
#define FUSED_COLS 18688
#define ROWS 4096      // B*N
#define KCAT 10240     // ATTN_IN + FF_IN

// ---------------- workspace layout (bytes) ----------------
constexpr size_t OFF_XN   = 0;
constexpr size_t OFF_Q    = 16777216;
constexpr size_t OFF_K    = 33554432;
constexpr size_t OFF_VT   = 34603008;
constexpr size_t OFF_ACAT = 35651584;
constexpr size_t OFF_GATE = 119537664;
constexpr size_t OFF_WFT  = 186646528;
constexpr size_t OFF_WCT  = 263192576;
// dead-region reuse:
//   attn partials: O_part bf16 over WFT; m/l fp32 over XN (dead after gemm1)
//   gemm2 split-K partials (bf16): P0 over XN [0,16MB), P1 over GATE (dead after silu)

// ---------------- LayerNorm -> bf16 ----------------
__global__ __launch_bounds__(256) void ln_kernel(const float* __restrict__ x,
                                                 const float* __restrict__ gamma,
                                                 __hip_bfloat16* __restrict__ xn) {
  int row = blockIdx.x;
  int tid = threadIdx.x;
  int lane = tid & 63, wave = tid >> 6;
  const float4* xr = (const float4*)(x + (size_t)row * DIMC);
  float4 a = xr[tid], b = xr[tid + 256];
  float s  = a.x + a.y + a.z + a.w + b.x + b.y + b.z + b.w;
  float ss = a.x*a.x + a.y*a.y + a.z*a.z + a.w*a.w + b.x*b.x + b.y*b.y + b.z*b.z + b.w*b.w;
  #pragma unroll
  for (int o = 32; o; o >>= 1) { s += __shfl_down(s, o); ss += __shfl_down(ss, o); }
  __shared__ float red[8];
  if (lane == 0) { red[wave] = s; red[4 + wave] = ss; }
  __syncthreads();
  s  = red[0] + red[1] + red[2] + red[3];
  ss = red[4] + red[5] + red[6] + red[7];
  float mean = s * (1.f / DIMC);
  float var  = ss * (1.f / DIMC) - mean * mean;
  float rstd = rsqrtf(var + 1e-5f);
  const float4* gp = (const float4*)gamma;
  float4 g1 = gp[tid], g2 = gp[tid + 256];
  __hip_bfloat16* o = xn + (size_t)row * DIMC;
  o[tid*4+0]      = __float2bfloat16((a.x - mean) * rstd * g1.x);
  o[tid*4+1]      = __float2bfloat16((a.y - mean) * rstd * g1.y);
  o[tid*4+2]      = __float2bfloat16((a.z - mean) * rstd * g1.z);
  o[tid*4+3]      = __float2bfloat16((a.w - mean) * rstd * g1.w);
  o[1024+tid*4+0] = __float2bfloat16((b.x - mean) * rstd * g2.x);
  o[1024+tid*4+1] = __float2bfloat16((b.y - mean) * rstd * g2.y);
  o[1024+tid*4+2] = __float2bfloat16((b.z - mean) * rstd * g2.z);
  o[1024+tid*4+3] = __float2bfloat16((b.w - mean) * rstd * g2.w);
}

// ---- fp32 [R][C] -> bf16 transposed dst[c*stride + off + r], 64x64 tile, bf16x8 writes ----
__global__ __launch_bounds__(256) void transpose_bf16(const float* __restrict__ src,
                                                      __hip_bfloat16* __restrict__ dst,
                                                      int R, int C, int dstStride, int dstOff) {
  __shared__ __align__(16) __hip_bfloat16 tile[64][72];
  int c0 = blockIdx.x * 64, r0 = blockIdx.y * 64;
  int tx = threadIdx.x & 15;
  int ty = threadIdx.x >> 4;
  #pragma unroll
  for (int i = 0; i < 64; i += 16) {
    float4 v = *(const float4*)(src + (size_t)(r0 + ty + i) * C + c0 + tx * 4);
    tile[tx*4+0][ty+i] = __float2bfloat16(v.x);
    tile[tx*4+1][ty+i] = __float2bfloat16(v.y);
    tile[tx*4+2][ty+i] = __float2bfloat16(v.z);
    tile[tx*4+3][ty+i] = __float2bfloat16(v.w);
  }
  __syncthreads();
  int rx = (threadIdx.x & 7) * 8;
  #pragma unroll
  for (int i = 0; i < 64; i += 32) {
    int cc = (threadIdx.x >> 3) + i;
    *(bf16x8*)(dst + (size_t)(c0 + cc) * dstStride + dstOff + r0 + rx) = *(const bf16x8*)&tile[cc][rx];
  }
}

// =========== 256x256 8-phase GEMM, m201-style read/wait discipline (round-9 best) ===========
struct GemmP {
  const __hip_bfloat16* A;
  const __hip_bfloat16* B;
  int K;
  int kTilesPer;
  int nbx;
  int nmn;
  int cpx;
  __hip_bfloat16* outF0;
  __hip_bfloat16* outF1;
  int Nout;
  __hip_bfloat16 *q, *kk, *vT, *acat, *gate;
};

#define LDA_Q(BUFIDX, QM) { \
    const char* slot_ = lds + ((BUFIDX) << 16) + ((QM) << 14); \
    _Pragma("unroll") for (int mi = 0; mi < 4; ++mi) \
    _Pragma("unroll") for (int ks = 0; ks < 2; ++ks) { \
      int row_ = (mi << 5) + (wr << 4) + (lane & 15); \
      int ch_  = (ks << 2) + (lane >> 4); \
      af[mi][ks] = *(const bf16x8*)(slot_ + (row_ << 7) + ((ch_ ^ (row_ & 7)) << 4)); } }

#define LDB_Q(DST, BUFIDX, QN) { \
    const char* slot_ = lds + ((BUFIDX) << 16) + 32768 + ((QN) << 14); \
    _Pragma("unroll") for (int ni = 0; ni < 2; ++ni) \
    _Pragma("unroll") for (int ks = 0; ks < 2; ++ks) { \
      int row_ = (ni << 6) + (wn << 4) + (lane & 15); \
      int ch_  = (ks << 2) + (lane >> 4); \
      DST[ni][ks] = *(const bf16x8*)(slot_ + (row_ << 7) + ((ch_ ^ (row_ & 7)) << 4)); } }

#define DO_MFMA_Q(QM, BSET, QN) \
    __builtin_amdgcn_s_setprio(1); \
    _Pragma("unroll") for (int mi = 0; mi < 4; ++mi) \
    _Pragma("unroll") for (int ni = 0; ni < 2; ++ni) \
    _Pragma("unroll") for (int ks = 0; ks < 2; ++ks) \
      acc[(QM)*4+mi][(QN)*2+ni] = __builtin_amdgcn_mfma_f32_16x16x32_bf16( \
          af[mi][ks], BSET[ni][ks], acc[(QM)*4+mi][(QN)*2+ni], 0, 0, 0); \
    __builtin_amdgcn_s_setprio(0);

#define KTILE_BODY(KT, BUFC) \
    LDB_Q(b0r, BUFC, 0); \
    LDA_Q(BUFC, 0); \
    stage(Bb, (KT) + 1, 1, 0); \
    asm volatile("s_waitcnt lgkmcnt(8)"); \
    __builtin_amdgcn_s_barrier(); \
    asm volatile("s_waitcnt lgkmcnt(0)"); \
    __builtin_amdgcn_sched_barrier(0); \
    DO_MFMA_Q(0, b0r, 0); \
    __builtin_amdgcn_s_barrier(); \
    LDB_Q(b1r, BUFC, 1); \
    stage(Bb, (KT) + 1, 1, 1); \
    __builtin_amdgcn_s_barrier(); \
    asm volatile("s_waitcnt lgkmcnt(0)"); \
    __builtin_amdgcn_sched_barrier(0); \
    DO_MFMA_Q(0, b1r, 1); \
    __builtin_amdgcn_s_barrier(); \
    LDA_Q(BUFC, 1); \
    stage(Ab, (KT) + 2, 0, 0); \
    __builtin_amdgcn_s_barrier(); \
    asm volatile("s_waitcnt lgkmcnt(0)"); \
    __builtin_amdgcn_sched_barrier(0); \
    DO_MFMA_Q(1, b0r, 0); \
    __builtin_amdgcn_s_barrier(); \
    stage(Ab, (KT) + 2, 0, 1); \
    asm volatile("s_waitcnt vmcnt(4)" ::: "memory"); \
    __builtin_amdgcn_sched_barrier(0); \
    __builtin_amdgcn_s_barrier(); \
    DO_MFMA_Q(1, b1r, 1);

template<int EPI>
__global__ __launch_bounds__(512, 2) void gemm256(GemmP p) {
  __shared__ __align__(16) char lds[131072];
  const int tid = threadIdx.x;
  const int lane = tid & 63, wave = tid >> 6;
  const int wr = wave >> 2, wn = wave & 3;

  int l = ((int)blockIdx.x & 7) * p.cpx + ((int)blockIdx.x >> 3);
  int kp = l / p.nmn;
  int r = l - kp * p.nmn;
  int per = 8 * p.nbx;
  int g = r / per;
  int rg = r - g * per;
  int by = (g << 3) + (rg & 7);
  int bx = rg >> 3;
  int m0 = by << 8, n0 = bx << 8;

  const int NT = p.kTilesPer;
  const size_t Kb = (size_t)p.K * 2;
  const size_t koff = (size_t)kp * NT * 128;
  const char* Ab = (const char*)p.A + (size_t)m0 * Kb + koff;
  const char* Bb = (const char*)p.B + (size_t)n0 * Kb + koff;

  auto stage = [&](const char* mbase, int ktTgt, int isB, int h) {
    int ks = ktTgt < NT ? ktTgt : NT - 1;
    char* dst = lds + ((ktTgt & 1) << 16) + (isB << 15) + (h << 14);
    #pragma unroll
    for (int j = 0; j < 2; ++j) {
      int c = (j << 9) + tid;
      int row = c >> 3;
      int gl = ((c & 7) ^ (row & 7)) << 4;
      __builtin_amdgcn_global_load_lds(
        (const __attribute__((address_space(1))) void*)(mbase + (size_t)((h << 7) + row) * Kb + (size_t)ks * 128 + gl),
        (__attribute__((address_space(3))) void*)(dst + (c << 4)), 16, 0, 0);
    }
  };

  bf16x8 af[4][2], b0r[2][2], b1r[2][2];
  f32x4 acc[8][4] = {};

  stage(Ab, 0, 0, 0); stage(Ab, 0, 0, 1);
  stage(Bb, 0, 1, 0); stage(Bb, 0, 1, 1);
  stage(Ab, 1, 0, 0); stage(Ab, 1, 0, 1);
  asm volatile("s_waitcnt vmcnt(4)" ::: "memory");
  __builtin_amdgcn_sched_barrier(0);
  __builtin_amdgcn_s_barrier();

  for (int kt = 0; kt < NT; kt += 2) {
    KTILE_BODY(kt, 0);
    KTILE_BODY(kt + 1, 1);
  }

  asm volatile("s_waitcnt vmcnt(0) lgkmcnt(0)" ::: "memory");

  if constexpr (EPI == 1) {
    #pragma unroll
    for (int mig = 0; mig < 8; ++mig) {
      int rr0 = m0 + (mig << 5) + (wr << 4) + ((lane >> 4) << 2);
      #pragma unroll
      for (int nig = 0; nig < 4; ++nig) {
        int cc = n0 + (nig << 6) + (wn << 4) + (lane & 15);
        #pragma unroll
        for (int rr_ = 0; rr_ < 4; ++rr_) {
          int rr = rr0 + rr_;
          int b = rr >> 11, n = rr & 2047;
          __hip_bfloat16 hv = __float2bfloat16(acc[mig][nig][rr_]);
          if (cc < 2048) {
            int h = cc >> 7, d = cc & 127;
            p.q[((((size_t)b << 4) + h) * NSEQ + n) * DHEAD + d] = hv;
          } else if (cc < 2176) {
            p.kk[(size_t)rr * DHEAD + (cc - 2048)] = hv;
          } else if (cc < 2304) {
            p.vT[(((size_t)b << 7) + (cc - 2176)) * NSEQ + n] = hv;
          } else if (cc < 10496) {
            p.acat[(size_t)rr * KCAT + (cc - 256)] = hv;
          } else {
            p.gate[(size_t)rr * FF_IN + (cc - 10496)] = hv;
          }
        }
      }
    }
  } else {
    __hip_bfloat16* dst = kp ? p.outF1 : p.outF0;
    #pragma unroll
    for (int mig = 0; mig < 8; ++mig) {
      int rr0 = m0 + (mig << 5) + (wr << 4) + ((lane >> 4) << 2);
      #pragma unroll
      for (int nig = 0; nig < 4; ++nig) {
        int cc = n0 + (nig << 6) + (wn << 4) + (lane & 15);
        #pragma unroll
        for (int rr_ = 0; rr_ < 4; ++rr_)
          dst[(size_t)(rr0 + rr_) * p.Nout + cc] = __float2bfloat16(acc[mig][nig][rr_]);
      }
    }
  }
}

// ---------------- split-K combine: bf16+bf16 -> fp32 out, x8 vectorized ----------------
__global__ __launch_bounds__(256) void addout_kernel(const __hip_bfloat16* __restrict__ a,
                                                     const __hip_bfloat16* __restrict__ b,
                                                     float* __restrict__ o, int n8) {
  int i = blockIdx.x * 256 + threadIdx.x;
  if (i < n8) {
    bf16x8 x = ((const bf16x8*)a)[i], y = ((const bf16x8*)b)[i];
    float4 o1, o2;
    o1.x = (float)x[0] + (float)y[0]; o1.y = (float)x[1] + (float)y[1];
    o1.z = (float)x[2] + (float)y[2]; o1.w = (float)x[3] + (float)y[3];
    o2.x = (float)x[4] + (float)y[4]; o2.y = (float)x[5] + (float)y[5];
    o2.z = (float)x[6] + (float)y[6]; o2.w = (float)x[7] + (float)y[7];
    ((float4*)o)[i * 2]     = o1;
    ((float4*)o)[i * 2 + 1] = o2;
  }
}

// ---------------- RoPE in place (k only; q fused into attn) ----------------
__global__ __launch_bounds__(256) void rope_kernel(__hip_bfloat16* __restrict__ t,
                                                   int totalRows, float scale) {
  int idx = blockIdx.x * 256 + threadIdx.x;
  if (idx >= totalRows * 64) return;
  int i = idx & 63;
  int row = idx >> 6;
  int n = row & (NSEQ - 1);
  float f = __expf(-(float)i * 0.14391157f);
  float ang = (float)n * f;
  float sv, cv;
  sincosf(ang, &sv, &cv);
  __hip_bfloat16* pp = t + (size_t)row * DHEAD;
  float x1 = __bfloat162float(pp[i]);
  float x2 = __bfloat162float(pp[i + 64]);
  pp[i]      = __float2bfloat16((x1 * cv - x2 * sv) * scale);
  pp[i + 64] = __float2bfloat16((x2 * cv + x1 * sv) * scale);
}

// ======== causal flash attention, split-KV partials (MQA), LDS-staged K/V (round-11 best) ========
__global__ __launch_bounds__(256, 2) void attn_part_kernel(const __hip_bfloat16* __restrict__ q,
                                                           const __hip_bfloat16* __restrict__ k,
                                                           const __hip_bfloat16* __restrict__ vT,
                                                           __hip_bfloat16* __restrict__ opart,
                                                           float* __restrict__ mpart,
                                                           float* __restrict__ lpart) {
  __shared__ __align__(16) char alds[81920];
  char* Ktile = alds;
  char* Vtile = alds + 32768;
  char* Pb    = alds + 65536;
  const int tid = threadIdx.x;
  int c = 79 - (int)blockIdx.x;
  int bh = blockIdx.y;
  int qt, ch;
  if (c < 8)       { qt = c;                 ch = 0; }
  else if (c < 24) { qt = 8  + ((c - 8) >> 1);  ch = (c - 8) & 1; }
  else if (c < 48) { qt = 16 + (c - 24) / 3;    ch = (c - 24) % 3; }
  else             { qt = 24 + ((c - 48) >> 2); ch = (c - 48) & 3; }
  int slot = bh * 80 + c;
  int b = bh >> 4;
  int lane = tid & 63, wave = tid >> 6;
  int q0 = qt << 6;
  int qrow0 = q0 + (wave << 4);
  const __hip_bfloat16* qbase = q + (size_t)bh * NSEQ * DHEAD;
  const char* kbase = (const char*)(k + (size_t)b * NSEQ * DHEAD);
  const char* vbase = (const char*)(vT + (size_t)b * DHEAD * NSEQ);
  char* Pw = Pb + (wave << 12);

  auto stageK = [&](int j0) {
    const char* kb = kbase + (size_t)j0 * 256;
    #pragma unroll
    for (int it = 0; it < 8; ++it) {
      int s = (it << 8) + tid;
      int row = s >> 4, cch = s & 15;
      int sch = (cch & 8) | ((cch & 7) ^ (row & 7));
      __builtin_amdgcn_global_load_lds(
        (const __attribute__((address_space(1))) void*)(kb + (size_t)row * 256 + (sch << 4)),
        (__attribute__((address_space(3))) void*)(Ktile + (s << 4)), 16, 0, 0);
    }
  };
  auto stageV = [&](int j0) {
    const char* vb = vbase + (size_t)j0 * 2;
    #pragma unroll
    for (int it = 0; it < 8; ++it) {
      int s = (it << 8) + tid;
      int row = s >> 4, cch = s & 15;
      int sch = (cch & 8) | ((cch & 7) ^ (row & 7));
      __builtin_amdgcn_global_load_lds(
        (const __attribute__((address_space(1))) void*)(vb + (size_t)row * (NSEQ * 2) + (sch << 4)),
        (__attribute__((address_space(3))) void*)(Vtile + (s << 4)), 16, 0, 0);
    }
  };

  bf16x8 qf[4];
  #pragma unroll
  for (int ks = 0; ks < 4; ++ks)
    qf[ks] = *(const bf16x8*)(qbase + (size_t)(qrow0 + (lane & 15)) * DHEAD + (ks << 5) + ((lane >> 4) << 3));
  {
    const float SCALE = 0.08838834764831845f;
    float nrow = (float)(qrow0 + (lane & 15));
    #pragma unroll
    for (int ks = 0; ks < 2; ++ks) {
      #pragma unroll
      for (int j = 0; j < 8; ++j) {
        int d = (ks << 5) + ((lane >> 4) << 3) + j;
        float f = __expf(-(float)d * 0.14391157f);
        float sv, cv;
        sincosf(nrow * f, &sv, &cv);
        float x1 = (float)qf[ks][j];
        float x2 = (float)qf[ks + 2][j];
        qf[ks][j]     = (__bf16)((x1 * cv - x2 * sv) * SCALE);
        qf[ks + 2][j] = (__bf16)((x2 * cv + x1 * sv) * SCALE);
      }
    }
  }
  f32x4 o[8] = {};
  float mrow[4] = {-1e30f, -1e30f, -1e30f, -1e30f};
  float lrow[4] = {0.f, 0.f, 0.f, 0.f};
  int nTiles = (q0 + 64 + 127) >> 7;
  int jBeg = ch << 2;
  int jEnd = jBeg + 4 < nTiles ? jBeg + 4 : nTiles;

  stageK(jBeg << 7);
  stageV(jBeg << 7);
  asm volatile("s_waitcnt vmcnt(0)" ::: "memory");
  __builtin_amdgcn_s_barrier();

  for (int j2 = jBeg; j2 < jEnd; ++j2) {
    int j0 = j2 << 7;
    bool more = (j2 + 1 < jEnd);
    f32x4 s[8] = {};
    #pragma unroll
    for (int ks = 0; ks < 4; ++ks) {
      bf16x8 kf2[8];
      #pragma unroll
      for (int nf = 0; nf < 8; ++nf) {
        int row_ = (nf << 4) + (lane & 15);
        int ch_  = (ks << 2) + (lane >> 4);
        int sch  = (ch_ & 8) | ((ch_ & 7) ^ (row_ & 7));
        kf2[nf] = *(const bf16x8*)(Ktile + (row_ << 8) + (sch << 4));
      }
      __builtin_amdgcn_s_setprio(1);
      #pragma unroll
      for (int nf = 0; nf < 8; ++nf)
        s[nf] = __builtin_amdgcn_mfma_f32_16x16x32_bf16(qf[ks], kf2[nf], s[nf], 0, 0, 0);
      __builtin_amdgcn_s_setprio(0);
    }
    __builtin_amdgcn_s_barrier();
    if (more) stageK((j0 + 128));
    if (j0 + 127 > q0) {
      #pragma unroll
      for (int nf = 0; nf < 8; ++nf) {
        int cg = j0 + (nf << 4) + (lane & 15);
        #pragma unroll
        for (int r = 0; r < 4; ++r) {
          int rg = qrow0 + ((lane >> 4) << 2) + r;
          if (cg > rg) s[nf][r] = -1e30f;
        }
      }
    }
    float tm[4] = {-1e30f, -1e30f, -1e30f, -1e30f};
    #pragma unroll
    for (int nf = 0; nf < 8; ++nf)
      #pragma unroll
      for (int r = 0; r < 4; ++r) tm[r] = fmaxf(tm[r], s[nf][r]);
    #pragma unroll
    for (int r = 0; r < 4; ++r) {
      #pragma unroll
      for (int msk = 1; msk < 16; msk <<= 1)
        tm[r] = fmaxf(tm[r], __shfl_xor(tm[r], msk));
    }
    float scl[4], ps[4] = {0.f, 0.f, 0.f, 0.f};
    #pragma unroll
    for (int r = 0; r < 4; ++r) {
      float mn = fmaxf(mrow[r], tm[r]);
      scl[r] = __expf(mrow[r] - mn);
      mrow[r] = mn;
    }
    #pragma unroll
    for (int nf = 0; nf < 8; ++nf) {
      #pragma unroll
      for (int r = 0; r < 4; ++r) {
        float pv = __expf(s[nf][r] - mrow[r]);
        ps[r] += pv;
        int prow = ((lane >> 4) << 2) + r;
        int pcol = (nf << 4) + (lane & 15);
        int pch  = pcol >> 3;
        int psch = (pch & 8) | ((pch & 7) ^ (prow & 7));
        *(__hip_bfloat16*)(Pw + (prow << 8) + (psch << 4) + ((pcol & 7) << 1)) = __float2bfloat16(pv);
      }
    }
    #pragma unroll
    for (int r = 0; r < 4; ++r) {
      #pragma unroll
      for (int msk = 1; msk < 16; msk <<= 1) ps[r] += __shfl_xor(ps[r], msk);
      lrow[r] = lrow[r] * scl[r] + ps[r];
    }
    #pragma unroll
    for (int df = 0; df < 8; ++df)
      #pragma unroll
      for (int r = 0; r < 4; ++r) o[df][r] *= scl[r];
    #pragma unroll
    for (int ks2 = 0; ks2 < 4; ++ks2) {
      int prow = lane & 15;
      int pch  = (ks2 << 2) + (lane >> 4);
      int psch = (pch & 8) | ((pch & 7) ^ (prow & 7));
      bf16x8 pf = *(const bf16x8*)(Pw + (prow << 8) + (psch << 4));
      bf16x8 vf2[8];
      #pragma unroll
      for (int df = 0; df < 8; ++df) {
        int row_ = (df << 4) + (lane & 15);
        int ch_  = (ks2 << 2) + (lane >> 4);
        int sch  = (ch_ & 8) | ((ch_ & 7) ^ (row_ & 7));
        vf2[df] = *(const bf16x8*)(Vtile + (row_ << 8) + (sch << 4));
      }
      __builtin_amdgcn_s_setprio(1);
      #pragma unroll
      for (int df = 0; df < 8; ++df)
        o[df] = __builtin_amdgcn_mfma_f32_16x16x32_bf16(pf, vf2[df], o[df], 0, 0, 0);
      __builtin_amdgcn_s_setprio(0);
    }
    if (more) {
      __builtin_amdgcn_s_barrier();
      stageV(j0 + 128);
      asm volatile("s_waitcnt vmcnt(0)" ::: "memory");
      __builtin_amdgcn_s_barrier();
    }
  }
  size_t rbase = ((size_t)slot << 6) + (wave << 4) + ((lane >> 4) << 2);
  #pragma unroll
  for (int df = 0; df < 8; ++df)
    #pragma unroll
    for (int r = 0; r < 4; ++r)
      opart[(rbase + r) * 128 + (df << 4) + (lane & 15)] = __float2bfloat16(o[df][r]);
  if ((lane & 15) == 0) {
    #pragma unroll
    for (int r = 0; r < 4; ++r) { mpart[rbase + r] = mrow[r]; lpart[rbase + r] = lrow[r]; }
  }
}

// combine: per (bh,row,8d) merge <=4 chunks; write acat attention columns (bf16x8)
__global__ __launch_bounds__(256) void attn_comb_kernel(const __hip_bfloat16* __restrict__ opart,
                                                        const float* __restrict__ mpart,
                                                        const float* __restrict__ lpart,
                                                        __hip_bfloat16* __restrict__ acat) {
  int t = blockIdx.x * 256 + threadIdx.x;
  int dg = t & 15;
  int rg = (t >> 4) & 2047;
  int bh = t >> 15;
  int qt = rg >> 6;
  int nc = (qt + 8) >> 3;
  int S = qt;
  if (qt >= 8)  S += qt - 8;
  if (qt >= 16) S += qt - 16;
  if (qt >= 24) S += qt - 24;
  size_t base = (((size_t)bh * 80 + S) << 6) + (rg & 63);
  float M = -1e30f;
  for (int cc = 0; cc < nc; ++cc) M = fmaxf(M, mpart[base + ((size_t)cc << 6)]);
  float O[8] = {};
  float L = 0.f;
  for (int cc = 0; cc < nc; ++cc) {
    size_t rb = base + ((size_t)cc << 6);
    float w = __expf(mpart[rb] - M);
    L += w * lpart[rb];
    bf16x8 ov = *(const bf16x8*)(opart + rb * 128 + (dg << 3));
    #pragma unroll
    for (int j = 0; j < 8; ++j) O[j] += w * (float)ov[j];
  }
  float invL = 1.f / L;
  int b = bh >> 4, h = bh & 15;
  bf16x8 res;
  #pragma unroll
  for (int j = 0; j < 8; ++j) res[j] = (__bf16)(O[j] * invL);
  *(bf16x8*)(acat + ((size_t)(b * 2048 + rg)) * KCAT + (h << 7) + (dg << 3)) = res;
}

// ---------------- silu(gate) * ff_x, in place on Acat (bf16x8) ----------------
__global__ __launch_bounds__(256) void silu_kernel(__hip_bfloat16* __restrict__ acat,
                                                   const __hip_bfloat16* __restrict__ gate) {
  size_t idx = ((size_t)blockIdx.x * 256 + threadIdx.x) << 3;
  int r = (int)(idx >> 13);
  int j = (int)(idx & 8191);
  bf16x8 g = *(const bf16x8*)(gate + idx);
  size_t ai = (size_t)r * KCAT + 2048 + j;
  bf16x8 fx = *(const bf16x8*)(acat + ai);
  bf16x8 res;
  #pragma unroll
  for (int t = 0; t < 8; ++t) {
    float gf = (float)g[t];
    res[t] = (__bf16)((float)fx[t] * gf / (1.f + __expf(-gf)));
  }
  *(bf16x8*)(acat + ai) = res;
}

extern "C" void kernel_launch(void* const* d_in, const int* in_sizes, int n_in,
                              void* d_out, int out_size, void* d_ws, size_t ws_size,
                              hipStream_t stream) {
  (void)in_sizes; (void)n_in; (void)out_size; (void)ws_size;
  const float* x          = (const float*)d_in[0];
  const float* gamma      = (const float*)d_in[1];
  const float* w_fused    = (const float*)d_in[2];
  const float* w_attn_out = (const float*)d_in[3];
  const float* w_ff_out   = (const float*)d_in[4];
  char* ws = (char*)d_ws;
  __hip_bfloat16* xn    = (__hip_bfloat16*)(ws + OFF_XN);
  __hip_bfloat16* qbuf  = (__hip_bfloat16*)(ws + OFF_Q);
  __hip_bfloat16* kbuf  = (__hip_bfloat16*)(ws + OFF_K);
  __hip_bfloat16* vTbuf = (__hip_bfloat16*)(ws + OFF_VT);
  __hip_bfloat16* acat  = (__hip_bfloat16*)(ws + OFF_ACAT);
  __hip_bfloat16* gateb = (__hip_bfloat16*)(ws + OFF_GATE);
  __hip_bfloat16* wfT   = (__hip_bfloat16*)(ws + OFF_WFT);
  __hip_bfloat16* wcT   = (__hip_bfloat16*)(ws + OFF_WCT);
  __hip_bfloat16* P0 = (__hip_bfloat16*)(ws + OFF_XN);
  __hip_bfloat16* P1 = (__hip_bfloat16*)(ws + OFF_GATE);
  __hip_bfloat16* oPart = (__hip_bfloat16*)(ws + OFF_WFT);
  float* mPart = (float*)(ws + OFF_XN);
  float* lPart = (float*)(ws + OFF_XN + 1048576);

  transpose_bf16<<<dim3(FUSED_COLS / 64, DIMC / 64), 256, 0, stream>>>(w_fused, wfT, DIMC, FUSED_COLS, DIMC, 0);
  transpose_bf16<<<dim3(DIMC / 64, DIMC / 64), 256, 0, stream>>>(w_attn_out, wcT, ATTN_IN, DIMC, KCAT, 0);
  transpose_bf16<<<dim3(DIMC / 64, FF_IN / 64), 256, 0, stream>>>(w_ff_out, wcT, FF_IN, DIMC, KCAT, ATTN_IN);

  ln_kernel<<<ROWS, 256, 0, stream>>>(x, gamma, xn);

  GemmP g1;
  g1.A = xn; g1.B = wfT; g1.K = DIMC; g1.kTilesPer = DIMC / 64;
  g1.nbx = FUSED_COLS / 256; g1.nmn = (FUSED_COLS / 256) * (ROWS / 256);
  g1.cpx = g1.nmn / 8;
  g1.outF0 = nullptr; g1.outF1 = nullptr; g1.Nout = 0;
  g1.q = qbuf; g1.kk = kbuf; g1.vT = vTbuf; g1.acat = acat; g1.gate = gateb;
  gemm256<1><<<g1.nmn, 512, 0, stream>>>(g1);

  rope_kernel<<<(BATCH * NSEQ * 64) / 256, 256, 0, stream>>>(kbuf, BATCH * NSEQ, 1.0f);

  attn_part_kernel<<<dim3(80, BATCH * HEADSC), 256, 0, stream>>>(qbuf, kbuf, vTbuf, oPart, mPart, lPart);
  attn_comb_kernel<<<(BATCH * HEADSC * NSEQ * DHEAD / 8) / 256, 256, 0, stream>>>(oPart, mPart, lPart, acat);

  silu_kernel<<<(int)(((size_t)ROWS * FF_IN / 8) / 256), 256, 0, stream>>>(acat, gateb);

  GemmP g2;
  g2.A = acat; g2.B = wcT; g2.K = KCAT; g2.kTilesPer = (KCAT / 64) / 2;
  g2.nbx = DIMC / 256; g2.nmn = (DIMC / 256) * (ROWS / 256);
  g2.cpx = (g2.nmn * 2) / 8;
  g2.outF0 = P0; g2.outF1 = P1; g2.Nout = DIMC;
  g2.q = nullptr; g2.kk = nullptr; g2.vT = nullptr; g2.acat = nullptr; g2.gate = nullptr;
  gemm256<3><<<g2.nmn * 2, 512, 0, stream>>>(g2);

  addout_kernel<<<(ROWS * DIMC / 8 + 255) / 256, 256, 0, stream>>>(P0, P1, (float*)d_out, ROWS * DIMC / 8);
}